// Round 2
// baseline (5692.079 us; speedup 1.0000x reference)
//
#include <hip/hip_runtime.h>
#include <cstdint>

#define B_    8
#define T_    16384
#define NA_   512
#define A_    512
#define NIT_  32
#define SEG_  1024
#define NSEG_ 16
#define EPSV  1e-8f

// order-preserving float<->uint encode (monotonic, bijective)
__device__ __forceinline__ unsigned int encf(float f) {
    unsigned int u = __float_as_uint(f);
    return (u & 0x80000000u) ? ~u : (u | 0x80000000u);
}
__device__ __forceinline__ float decf(unsigned int e) {
    unsigned int u = (e & 0x80000000u) ? (e & 0x7fffffffu) : ~e;
    return __uint_as_float(u);
}
__device__ __forceinline__ unsigned long long shfl_xor_u64(unsigned long long v, int mask) {
    unsigned int lo = (unsigned int)v, hi = (unsigned int)(v >> 32);
    lo = __shfl_xor(lo, mask, 64);
    hi = __shfl_xor(hi, mask, 64);
    return (((unsigned long long)hi) << 32) | lo;
}

// ---------------- normalize atoms: dn = d / (||d|| + eps) ----------------
__global__ __launch_bounds__(256) void k_norm(const float* __restrict__ d,
                                              float* __restrict__ dn) {
    const int a = blockIdx.x;
    const int tid = threadIdx.x;
    const float* row = d + a * A_;
    float s = 0.f;
    for (int i = tid; i < A_; i += 256) { float v = row[i]; s += v * v; }
    #pragma unroll
    for (int o = 32; o > 0; o >>= 1) s += __shfl_down(s, o, 64);
    __shared__ float ls[4];
    if ((tid & 63) == 0) ls[tid >> 6] = s;
    __syncthreads();
    __shared__ float den_s;
    if (tid == 0) den_s = sqrtf(ls[0] + ls[1] + ls[2] + ls[3]) + EPSV;
    __syncthreads();
    float den = den_s;
    for (int i = tid; i < A_; i += 256) dn[a * A_ + i] = row[i] / den;
}

// ---------------- zero a u64 table ----------------
__global__ void k_init(unsigned long long* __restrict__ seg, int n) {
    int i = blockIdx.x * 256 + threadIdx.x;
    if (i < n) seg[i] = 0ull;   // 0 < enc of any real float in our data
}

// ---------------- initial full correlation fm[gb,a,t] + u64 seg table ----------------
// tile: 64 atoms x 128 t per block, K over 512 in steps of 32.
__global__ __launch_bounds__(256) void k_conv(const float* __restrict__ x,
                                              const float* __restrict__ dn,
                                              float* __restrict__ fm,
                                              unsigned long long* __restrict__ seg0,
                                              int bg0) {
    __shared__ float As[32][68];
    __shared__ float Xs[160];
    const int tid = threadIdx.x;
    const int t0 = blockIdx.x * 128;
    const int a0 = blockIdx.y * 64;
    const int gb = blockIdx.z;
    const int tt = tid & 31;
    const int mb = tid >> 5;
    const float* xb = x + (bg0 + gb) * T_;

    float acc[8][4];
    #pragma unroll
    for (int p = 0; p < 8; ++p)
        #pragma unroll
        for (int q = 0; q < 4; ++q) acc[p][q] = 0.f;

    for (int k0 = 0; k0 < A_; k0 += 32) {
        #pragma unroll
        for (int mm = 0; mm < 8; ++mm) {
            int m = mb * 8 + mm;
            As[tt][m] = dn[(a0 + m) * A_ + k0 + tt];
        }
        if (tid < 160) {
            int g = t0 + k0 + tid;
            Xs[tid] = (g < T_) ? xb[g] : 0.f;
        }
        __syncthreads();
        #pragma unroll 8
        for (int k = 0; k < 32; ++k) {
            float4 aA = *(const float4*)&As[k][mb * 8];
            float4 aB = *(const float4*)&As[k][mb * 8 + 4];
            float am[8] = {aA.x, aA.y, aA.z, aA.w, aB.x, aB.y, aB.z, aB.w};
            float xm[4] = {Xs[k + tt], Xs[k + tt + 32], Xs[k + tt + 64], Xs[k + tt + 96]};
            #pragma unroll
            for (int p = 0; p < 8; ++p)
                #pragma unroll
                for (int q = 0; q < 4; ++q)
                    acc[p][q] = fmaf(am[p], xm[q], acc[p][q]);
        }
        __syncthreads();
    }

    const int sidx = t0 >> 10;   // whole block inside one 1024-wide segment
    #pragma unroll
    for (int p = 0; p < 8; ++p) {
        int m = mb * 8 + p;
        size_t row = (size_t)(gb * NA_ + a0 + m) * T_;
        unsigned long long cand = 0ull;
        #pragma unroll
        for (int q = 0; q < 4; ++q) {
            int t = t0 + tt + 32 * q;
            fm[row + t] = acc[p][q];
            unsigned int flat = (unsigned int)((a0 + m) * T_ + t);
            unsigned long long c = (((unsigned long long)encf(acc[p][q])) << 32) | (unsigned int)~flat;
            if (c > cand) cand = c;
        }
        #pragma unroll
        for (int o = 1; o < 32; o <<= 1) {   // reduce across the 32-lane t-group
            unsigned long long c = shfl_xor_u64(cand, o);
            if (c > cand) cand = c;
        }
        if (tt == 0)
            atomicMax(&seg0[(size_t)gb * NA_ * NSEG_ + (a0 + m) * NSEG_ + sidx], cand);
    }
}

// ---------------- fused per-iteration kernel ----------------
// Every block: (A) derive the selection from the immutable segOld table,
// (B) incrementally update its own fm row over the <=1023-wide window,
// (C) write its row's 16 entries into segNew (14 copied, <=2 rescanned).
__global__ __launch_bounds__(128) void k_iter(float* __restrict__ fm,
                                              const float* __restrict__ dn,
                                              const unsigned long long* __restrict__ segOld,
                                              unsigned long long* __restrict__ segNew,
                                              int* __restrict__ selA,
                                              int* __restrict__ selT,
                                              float* __restrict__ selV,
                                              int it, int bg0) {
    __shared__ unsigned long long redU[128];
    __shared__ float dnA[A_];
    __shared__ float w[A_ + 8];
    __shared__ int selSh[2];
    __shared__ float vSh;
    const int aB = blockIdx.x;
    const int gb = blockIdx.y;
    const int tid = threadIdx.x;

    // ---- phase A: selection (all blocks compute identical result) ----
    const unsigned long long* tab = segOld + (size_t)gb * (NA_ * NSEG_);
    unsigned long long best = 0ull;
    for (int k = 0; k < 64; ++k) {
        unsigned long long c = tab[tid + 128 * k];
        if (c > best) best = c;
    }
    redU[tid] = best;
    __syncthreads();
    for (int s = 64; s > 0; s >>= 1) {
        if (tid < s) { if (redU[tid + s] > redU[tid]) redU[tid] = redU[tid + s]; }
        __syncthreads();
    }
    if (tid == 0) {
        unsigned long long win = redU[0];
        unsigned int enc  = (unsigned int)(win >> 32);
        unsigned int flat = ~(unsigned int)win;
        selSh[0] = (int)(flat >> 14);       // atom
        selSh[1] = (int)(flat & (T_ - 1));  // time
        vSh = decf(enc);                    // exact fm value
        if (aB == 0) {
            int b = bg0 + gb;
            selA[it * B_ + b] = selSh[0];
            selT[it * B_ + b] = selSh[1];
            selV[it * B_ + b] = vSh;
        }
    }
    __syncthreads();
    const int asel = selSh[0];
    const int tsel = selSh[1];
    const float v  = vSh;
    const int L = min(A_, (T_ - 1) - tsel);  // reference truncation quirk

    const size_t rowoff = (size_t)(gb * NA_ + aB) * T_;
    unsigned long long* nrow = segNew + (size_t)gb * (NA_ * NSEG_) + aB * NSEG_;
    const unsigned long long* orow = tab + aB * NSEG_;

    int s0 = NSEG_, s1 = -1;
    if (L > 0) {
        for (int i = tid; i < A_; i += 128) {
            dnA[i] = dn[aB * A_ + i];
            w[i]   = v * dn[asel * A_ + i];
        }
        __syncthreads();

        const int tbeg = max(0, tsel - (A_ - 1));
        const int tend = tsel + L;            // exclusive
        s0 = tbeg >> 10;
        s1 = (tend - 1) >> 10;

        // Δfm[aB, tsel+τ] = Σ_j dnA[j-τ]·w[j];  thread owns τ = tau0..tau0+7
        const int tau0 = (tbeg - tsel) + tid * 8;
        float acc[8] = {0,0,0,0,0,0,0,0};
        float h[8];
        const int js = max(0, tau0);
        const int je = min(L, tau0 + A_ + 7);
        #pragma unroll
        for (int m = 1; m < 8; ++m) {          // ring preload
            int idx = js - 8 + m - tau0;
            h[m] = (idx >= 0 && idx < A_) ? dnA[idx] : 0.f;
        }
        h[0] = 0.f;
        for (int j = js; j < je; j += 8) {
            #pragma unroll
            for (int u = 0; u < 8; ++u) {
                int jj = j + u;
                int idx = jj - tau0;           // >= 0 always
                float nd = (idx < A_) ? dnA[idx & (A_ - 1)] : 0.f;
                h[u] = nd;
                float wj = (jj < je) ? w[jj] : 0.f;
                #pragma unroll
                for (int k = 0; k < 8; ++k)
                    acc[k] = fmaf(h[(u - k) & 7], wj, acc[k]);
            }
        }
        #pragma unroll
        for (int k = 0; k < 8; ++k) {
            int t = tbeg + tid * 8 + k;        // coalesced
            if (t < tend) fm[rowoff + t] -= acc[k];
        }
        __syncthreads();                       // fm writes visible to this block
    }

    // ---- phase C: seg table for this row -> segNew ----
    if (tid < NSEG_ && (tid < s0 || tid > s1)) nrow[tid] = orow[tid];
    for (int s = s0; s <= s1; ++s) {
        const float* rp = fm + rowoff + s * SEG_;
        unsigned long long m = 0ull;
        for (int i = tid; i < SEG_; i += 128) {
            unsigned int flat = (unsigned int)(aB * T_ + s * SEG_ + i);
            unsigned long long c = (((unsigned long long)encf(rp[i])) << 32) | (unsigned int)~flat;
            if (c > m) m = c;
        }
        __syncthreads();
        redU[tid] = m;
        __syncthreads();
        for (int t2 = 64; t2 > 0; t2 >>= 1) {
            if (tid < t2) { if (redU[tid + t2] > redU[tid]) redU[tid] = redU[tid + t2]; }
            __syncthreads();
        }
        if (tid == 0) nrow[s] = redU[0];
        __syncthreads();
    }
}

// ---------------- slow fallback (tiny ws): recompute conv from residual ----------------
__global__ void s_init(const float* __restrict__ x, float* __restrict__ xr,
                       unsigned long long* __restrict__ cand) {
    int i = blockIdx.x * 256 + threadIdx.x;
    if (i < B_ * T_) xr[i] = x[i];
    if (i < B_) cand[i] = 0ull;
}
__global__ __launch_bounds__(256) void s_scan(const float* __restrict__ xr,
                                              const float* __restrict__ dn,
                                              unsigned long long* __restrict__ cand) {
    __shared__ float dL[A_];
    __shared__ unsigned long long redU[256];
    const int aB = blockIdx.x, b = blockIdx.y, tid = threadIdx.x;
    for (int i = tid; i < A_; i += 256) dL[i] = dn[aB * A_ + i];
    __syncthreads();
    const float* xb = xr + b * T_;
    unsigned long long best = 0ull;
    for (int t = tid; t < T_; t += 256) {
        float acc = 0.f;
        int lim = min(A_, T_ - t);
        for (int i = 0; i < lim; ++i) acc = fmaf(dL[i], xb[t + i], acc);
        unsigned int flat = (unsigned int)(aB * T_ + t);
        unsigned long long c = (((unsigned long long)encf(acc)) << 32) | (unsigned int)~flat;
        if (c > best) best = c;
    }
    redU[tid] = best;
    __syncthreads();
    for (int s = 128; s > 0; s >>= 1) {
        if (tid < s) { if (redU[tid + s] > redU[tid]) redU[tid] = redU[tid + s]; }
        __syncthreads();
    }
    if (tid == 0) atomicMax(&cand[b], redU[0]);
}
__global__ void s_apply(float* __restrict__ xr, const float* __restrict__ dn,
                        unsigned long long* __restrict__ cand,
                        int* selA, int* selT, float* selV, int it) {
    const int b = blockIdx.x, tid = threadIdx.x;
    unsigned long long win = cand[b];
    unsigned int enc  = (unsigned int)(win >> 32);
    unsigned int flat = ~(unsigned int)win;
    int a = (int)(flat >> 14), t = (int)(flat & (T_ - 1));
    float v = decf(enc);
    if (tid == 0) { selA[it * B_ + b] = a; selT[it * B_ + b] = t; selV[it * B_ + b] = v; }
    int L = min(A_, (T_ - 1) - t);
    for (int o = tid; o < L; o += 256) xr[b * T_ + t + o] -= v * dn[a * A_ + o];
    if (tid == 0) cand[b] = 0ull;
}

// ---------------- reconstruct (residual, recon) from the 32x8 selections ----------------
__global__ __launch_bounds__(256) void k_final(const float* __restrict__ x,
                                               const float* __restrict__ dn,
                                               const int* __restrict__ selA,
                                               const int* __restrict__ selT,
                                               const float* __restrict__ selV,
                                               float* __restrict__ out) {
    const int gid = blockIdx.x * 256 + threadIdx.x;  // 0..131071
    const int b = gid >> 14;
    const int t = gid & (T_ - 1);
    float r = x[gid];
    float rec = 0.f;
    for (int k = 0; k < NIT_; ++k) {     // sequential: reference fp order
        int a   = selA[k * B_ + b];
        int ts  = selT[k * B_ + b];
        float v = selV[k * B_ + b];
        int o = t - ts;
        int L = min(A_, (T_ - 1) - ts);
        if (o >= 0 && o < L) {
            float c = v * dn[a * A_ + o];
            r -= c;
            rec += c;
        }
    }
    out[gid] = r;
    out[B_ * T_ + gid] = rec;
}

extern "C" void kernel_launch(void* const* d_in, const int* in_sizes, int n_in,
                              void* d_out, int out_size, void* d_ws, size_t ws_size,
                              hipStream_t stream) {
    const float* x = (const float*)d_in[0];
    const float* d = (const float*)d_in[1];
    float* out = (float*)d_out;
    float* ws = (float*)d_ws;
    const size_t wsf = ws_size / sizeof(float);

    // common layout (floats): dn | sel | dynamic
    const size_t OFF_DN  = 0;                      // 262144
    const size_t OFF_SEL = OFF_DN + (size_t)NA_ * A_;
    const size_t OFF_DYN = OFF_SEL + 1024;         // 263168 (8B-aligned)
    float* dn   = ws + OFF_DN;
    int*   selA = (int*)(ws + OFF_SEL);
    int*   selT = selA + NIT_ * B_;
    float* selV = (float*)(selT + NIT_ * B_);

    // pick largest batch-group G whose fm fits:
    // need = OFF_DYN + 2 seg tables (G*8192 u64 each) + fm (G*512*16384 f32)
    int G = 0;
    for (int g = 8; g >= 1; g >>= 1) {
        size_t need = OFF_DYN + (size_t)g * NA_ * NSEG_ * 2 * 2 + (size_t)g * NA_ * T_;
        if (need <= wsf) { G = g; break; }
    }

    k_norm<<<dim3(NA_), dim3(256), 0, stream>>>(d, dn);

    if (G > 0) {
        unsigned long long* segA = (unsigned long long*)(ws + OFF_DYN);
        unsigned long long* segB = segA + (size_t)G * NA_ * NSEG_;
        float* fm = ws + OFF_DYN + (size_t)G * NA_ * NSEG_ * 2 * 2;
        const int nseg_ents = G * NA_ * NSEG_;
        for (int bg0 = 0; bg0 < B_; bg0 += G) {
            k_init<<<dim3((nseg_ents + 255) / 256), dim3(256), 0, stream>>>(segA, nseg_ents);
            k_conv<<<dim3(T_ / 128, NA_ / 64, G), dim3(256), 0, stream>>>(x, dn, fm, segA, bg0);
            for (int it = 0; it < NIT_; ++it) {
                unsigned long long* so = (it & 1) ? segB : segA;
                unsigned long long* sn = (it & 1) ? segA : segB;
                k_iter<<<dim3(NA_, G), dim3(128), 0, stream>>>(fm, dn, so, sn,
                                                               selA, selT, selV, it, bg0);
            }
        }
    } else {
        // slow fallback: residual-space recompute (~1.6 MiB ws)
        float* xr = ws + OFF_DYN;
        unsigned long long* cand = (unsigned long long*)(ws + OFF_DYN + (size_t)B_ * T_);
        if (OFF_DYN + (size_t)B_ * T_ + 16 > wsf) return;  // hopeless
        s_init<<<dim3((B_ * T_ + 255) / 256), dim3(256), 0, stream>>>(x, xr, cand);
        for (int it = 0; it < NIT_; ++it) {
            s_scan<<<dim3(NA_, B_), dim3(256), 0, stream>>>(xr, dn, cand);
            s_apply<<<dim3(B_), dim3(256), 0, stream>>>(xr, dn, cand, selA, selT, selV, it);
        }
    }

    k_final<<<dim3(B_ * T_ / 256), dim3(256), 0, stream>>>(x, dn, selA, selT, selV, out);
}